// Round 17
// baseline (915.270 us; speedup 1.0000x reference)
//
#include <hip/hip_runtime.h>
#include <math.h>

#define NB 8
#define N0 16384
#define NC 128
#define NE 98304

typedef unsigned short ushort_t;
using short8 = __attribute__((ext_vector_type(8))) short;
using f32x4 = __attribute__((ext_vector_type(4))) float;

// ---------- helpers ----------
__device__ __forceinline__ unsigned mono_u(float f) {
  unsigned u = __float_as_uint(f);
  return (u & 0x80000000u) ? ~u : (u | 0x80000000u);
}
__device__ __forceinline__ int f2ikey(float f) {
  int i = __float_as_int(f);
  return (i >= 0) ? i : (i ^ 0x7fffffff);
}
__device__ __forceinline__ float ikey2f(int k) {
  return __int_as_float(k >= 0 ? k : (k ^ 0x7fffffff));
}
__device__ __forceinline__ ushort_t f2bf_rne(float f) {
  unsigned u = __float_as_uint(f);
  unsigned r = u + 0x7fffu + ((u >> 16) & 1u);
  return (ushort_t)(r >> 16);
}
__device__ __forceinline__ int wscan_incl(int v, int lane) {
#pragma unroll
  for (int o = 1; o < 64; o <<= 1) {
    int u = __shfl_up(v, o);
    if (lane >= o) v += u;
  }
  return v;
}

// ---------- init: edges copy + depth-0 degree count, readout bufs ----------
// cnt must be pre-zeroed.
__global__ void k_init(const int* __restrict__ src, const int* __restrict__ dst,
                       int* __restrict__ srcw, int* __restrict__ dstw,
                       int* __restrict__ cnt, int* __restrict__ maxbuf, float* __restrict__ sumbuf) {
  int stride = gridDim.x * blockDim.x;
  int i = blockIdx.x * blockDim.x + threadIdx.x;
  for (int j = i; j < NB * NE; j += stride) {
    int d = dst[j];
    srcw[j] = src[j];
    dstw[j] = d;
    atomicAdd(&cnt[(j / NE) * N0 + d], 1);
  }
  for (int j = i; j < 4 * NB * NC; j += stride) {
    maxbuf[j] = (int)0x80000000;
    sumbuf[j] = 0.f;
  }
}

// ---------- weight prep (all 8 matrices in one launch): W[k][c] f32 -> Wt[c][k] bf16 ----------
__global__ void k_wprep8(const float* w0, const float* w1, const float* w2, const float* w3,
                         const float* w4, const float* w5, const float* w6, const float* w7,
                         ushort_t* __restrict__ Wt_all) {
  int id = blockIdx.x * blockDim.x + threadIdx.x;
  if (id >= 8 * NC * NC) return;
  int m = id >> 14, e = id & (NC * NC - 1);
  const float* W;
  switch (m) {
    case 0: W = w0; break;
    case 1: W = w1; break;
    case 2: W = w2; break;
    case 3: W = w3; break;
    case 4: W = w4; break;
    case 5: W = w5; break;
    case 6: W = w6; break;
    default: W = w7; break;
  }
  int kk = e >> 7, c = e & 127;
  Wt_all[(size_t)m * NC * NC + c * NC + kk] = f2bf_rne(W[e]);
}

// ---------- CSR build: per-graph exclusive scan (wave-shuffle); zeroes cnt ----------
__global__ __launch_bounds__(1024) void k_scan(int* __restrict__ cnt,
                                               int* __restrict__ offs, int* __restrict__ cursor) {
  __shared__ int wsum[16];
  int b = blockIdx.x, t = threadIdx.x, lane = t & 63, wid = t >> 6;
  int base = b * N0 + t * 16;
  int loc[16];
  int s = 0;
#pragma unroll
  for (int j = 0; j < 16; j++) { loc[j] = cnt[base + j]; s += loc[j]; cnt[base + j] = 0; }
  int incl = wscan_incl(s, lane);
  if (lane == 63) wsum[wid] = incl;
  __syncthreads();
  int woff = 0;
  for (int w = 0; w < wid; w++) woff += wsum[w];
  int excl = woff + incl - s;
#pragma unroll
  for (int j = 0; j < 16; j++) {
    offs[base + j] = excl;
    cursor[base + j] = excl;
    excl += loc[j];
  }
}

// ---------- CSR build: fill edge list; cursor ends as end-offset ----------
// NOTE: atomic placement order determines elist order -> summation order.
// Do NOT change this kernel's launch shape (numerics-sensitive downstream).
__global__ void k_fill(const int* __restrict__ srcw, const int* __restrict__ dstw,
                       int* __restrict__ cursor, int* __restrict__ elist) {
  int tot = NB * NE;
  for (int i = blockIdx.x * blockDim.x + threadIdx.x; i < tot; i += gridDim.x * blockDim.x) {
    int d = dstw[i];
    if (d < 0) continue;
    int b = i / NE;
    int pos = atomicAdd(&cursor[b * N0 + d], 1);
    elist[b * NE + pos] = srcw[i];
  }
}

// ---------- FUSED gather + GIN MLP ----------
// Block = 512 thr / 8 waves, tile = 128 rows. Wave w gathers rows w*16..w*16+15
// (k_gather per-node body VERBATIM -> bit-identical h0) into its own Ts rows,
// then proceeds to pass-1 MFMA on those same rows WITHOUT a block barrier
// (Wsh/W1 was barriered before the gather; Ts rows are wave-private).
// Waves finishing gather early overlap MFMA with other waves' memory phase.
__global__ __launch_bounds__(512) void k_gg(const float* __restrict__ X,
                                            const int* __restrict__ offs,
                                            const int* __restrict__ cend,
                                            const int* __restrict__ elist,
                                            const ushort_t* __restrict__ W1t,
                                            const float* __restrict__ b1,
                                            const ushort_t* __restrict__ W2t,
                                            const float* __restrict__ b2,
                                            const float* __restrict__ pw,
                                            float* __restrict__ Xout,
                                            float* __restrict__ score, int n) {
  __shared__ ushort_t Ts[128 * 136];
  __shared__ ushort_t Wsh[128 * 136];
  int b = blockIdx.x & 7;
  int r0 = (blockIdx.x >> 3) * 128;
  int t = threadIdx.x, lane = t & 63, w = t >> 6;

  // stage W1 + prefetch W2 fragments to registers
  short8 w2r[4];
#pragma unroll
  for (int p = 0; p < 4; p++) {
    int id = t + p * 512;
    int row = id >> 4, seg = id & 15;
    *reinterpret_cast<short8*>(&Wsh[row * 136 + seg * 8]) =
        *reinterpret_cast<const short8*>(&W1t[row * NC + seg * 8]);
    w2r[p] = *reinterpret_cast<const short8*>(&W2t[row * NC + seg * 8]);
  }
  __syncthreads();  // Wsh(W1) ready; everything below is wave-private until next barrier

  // ---- gather phase (k_gather body verbatim per node) ----
  {
    int h = lane >> 5, c4 = lane & 31;
    const float* Xb = X + (size_t)b * N0 * NC;
    for (int i = 0; i < 16; i++) {
      int row = w * 16 + i;
      int node = r0 + row;
      if (node < n) {
        int off = offs[b * N0 + node];
        int deg = cend[b * N0 + node] - off;
        float4 acc0 = make_float4(0.f, 0.f, 0.f, 0.f);
        float4 acc1 = make_float4(0.f, 0.f, 0.f, 0.f);
        if (h == 0) acc0 = *reinterpret_cast<const float4*>(&Xb[(size_t)node * NC + c4 * 4]);
        for (int base = 0; base < deg; base += 64) {
          int m = min(64, deg - base);
          int eid = (lane < m) ? elist[b * NE + off + base + lane] : 0;
          int j = 0;
          for (; j + 4 <= m; j += 4) {
            int s0 = __shfl(eid, j + h);
            int s1 = __shfl(eid, j + 2 + h);
            float4 v0 = *reinterpret_cast<const float4*>(&Xb[(size_t)s0 * NC + c4 * 4]);
            float4 v1 = *reinterpret_cast<const float4*>(&Xb[(size_t)s1 * NC + c4 * 4]);
            acc0.x += v0.x; acc0.y += v0.y; acc0.z += v0.z; acc0.w += v0.w;
            acc1.x += v1.x; acc1.y += v1.y; acc1.z += v1.z; acc1.w += v1.w;
          }
          if (j + 2 <= m) {
            int s0 = __shfl(eid, j + h);
            float4 v0 = *reinterpret_cast<const float4*>(&Xb[(size_t)s0 * NC + c4 * 4]);
            acc0.x += v0.x; acc0.y += v0.y; acc0.z += v0.z; acc0.w += v0.w;
            j += 2;
          }
          if (j < m) {
            int s0 = __shfl(eid, j);
            if (h == 0) {
              float4 v0 = *reinterpret_cast<const float4*>(&Xb[(size_t)s0 * NC + c4 * 4]);
              acc0.x += v0.x; acc0.y += v0.y; acc0.z += v0.z; acc0.w += v0.w;
            }
          }
        }
        acc0.x += acc1.x; acc0.y += acc1.y; acc0.z += acc1.z; acc0.w += acc1.w;
        acc0.x += __shfl_xor(acc0.x, 32);
        acc0.y += __shfl_xor(acc0.y, 32);
        acc0.z += __shfl_xor(acc0.z, 32);
        acc0.w += __shfl_xor(acc0.w, 32);
        if (h == 0) {
          unsigned p0 = (unsigned)f2bf_rne(acc0.x) | ((unsigned)f2bf_rne(acc0.y) << 16);
          unsigned p1 = (unsigned)f2bf_rne(acc0.z) | ((unsigned)f2bf_rne(acc0.w) << 16);
          *reinterpret_cast<uint2*>(&Ts[row * 136 + c4 * 4]) = make_uint2(p0, p1);
        }
      } else {
        if (h == 0)
          *reinterpret_cast<uint2*>(&Ts[row * 136 + c4 * 4]) = make_uint2(0u, 0u);
      }
    }
  }
  // NO block barrier here: pass 1 below reads only this wave's own Ts rows.

  int li = lane & 15, lg = lane >> 4;
  int rbase = w * 16;

  f32x4 acc[8];
#pragma unroll
  for (int ct = 0; ct < 8; ct++) acc[ct] = (f32x4)0.f;

  // ---- pass 1: T1 = h0 @ W1 ----
#pragma unroll
  for (int ks = 0; ks < 4; ks++) {
    short8 x0 = *reinterpret_cast<const short8*>(&Ts[(rbase + li) * 136 + ks * 32 + lg * 8]);
#pragma unroll
    for (int ct = 0; ct < 8; ct++) {
      short8 wf = *reinterpret_cast<const short8*>(&Wsh[(ct * 16 + li) * 136 + ks * 32 + lg * 8]);
      acc[ct] = __builtin_amdgcn_mfma_f32_16x16x32_bf16(wf, x0, acc[ct], 0, 0, 0);
    }
  }

  // ---- epilogue 1: relu+bias -> bf16 back into own Ts rows ----
  {
    int row = rbase + li;
#pragma unroll
    for (int ct = 0; ct < 8; ct++) {
      float4 bq = *reinterpret_cast<const float4*>(&b1[ct * 16 + lg * 4]);
      float o0 = fmaxf(acc[ct][0] + bq.x, 0.f);
      float o1 = fmaxf(acc[ct][1] + bq.y, 0.f);
      float o2 = fmaxf(acc[ct][2] + bq.z, 0.f);
      float o3 = fmaxf(acc[ct][3] + bq.w, 0.f);
      unsigned p0 = (unsigned)f2bf_rne(o0) | ((unsigned)f2bf_rne(o1) << 16);
      unsigned p1 = (unsigned)f2bf_rne(o2) | ((unsigned)f2bf_rne(o3) << 16);
      *reinterpret_cast<uint2*>(&Ts[row * 136 + ct * 16 + lg * 4]) = make_uint2(p0, p1);
    }
  }

  __syncthreads();  // all waves done with Wsh(W1); restage W2
#pragma unroll
  for (int p = 0; p < 4; p++) {
    int id = t + p * 512;
    int row = id >> 4, seg = id & 15;
    *reinterpret_cast<short8*>(&Wsh[row * 136 + seg * 8]) = w2r[p];
  }
  __syncthreads();

#pragma unroll
  for (int ct = 0; ct < 8; ct++) acc[ct] = (f32x4)0.f;

  // ---- pass 2: x2 = T1 @ W2 ----
#pragma unroll
  for (int ks = 0; ks < 4; ks++) {
    short8 x0 = *reinterpret_cast<const short8*>(&Ts[(rbase + li) * 136 + ks * 32 + lg * 8]);
#pragma unroll
    for (int ct = 0; ct < 8; ct++) {
      short8 wf = *reinterpret_cast<const short8*>(&Wsh[(ct * 16 + li) * 136 + ks * 32 + lg * 8]);
      acc[ct] = __builtin_amdgcn_mfma_f32_16x16x32_bf16(wf, x0, acc[ct], 0, 0, 0);
    }
  }

  // ---- epilogue 2: relu+bias, float4 stores, fused score ----
  f32x4 pq[8];
  float psum = 0.f;
#pragma unroll
  for (int ct = 0; ct < 8; ct++) {
    pq[ct] = *reinterpret_cast<const f32x4*>(&pw[ct * 16 + lg * 4]);
    psum = fmaf(pq[ct][0], pq[ct][0], psum);
    psum = fmaf(pq[ct][1], pq[ct][1], psum);
    psum = fmaf(pq[ct][2], pq[ct][2], psum);
    psum = fmaf(pq[ct][3], pq[ct][3], psum);
  }
  psum += __shfl_xor(psum, 16);
  psum += __shfl_xor(psum, 32);
  float nrm = sqrtf(psum);

  float* Ob = Xout + (size_t)b * N0 * NC;
  {
    int row = r0 + rbase + li;
    bool ok = row < n;
    float dot = 0.f;
#pragma unroll
    for (int ct = 0; ct < 8; ct++) {
      float4 bq = *reinterpret_cast<const float4*>(&b2[ct * 16 + lg * 4]);
      float4 o;
      o.x = fmaxf(acc[ct][0] + bq.x, 0.f);
      o.y = fmaxf(acc[ct][1] + bq.y, 0.f);
      o.z = fmaxf(acc[ct][2] + bq.z, 0.f);
      o.w = fmaxf(acc[ct][3] + bq.w, 0.f);
      dot = fmaf(o.x, pq[ct][0], dot);
      dot = fmaf(o.y, pq[ct][1], dot);
      dot = fmaf(o.z, pq[ct][2], dot);
      dot = fmaf(o.w, pq[ct][3], dot);
      if (ok) *reinterpret_cast<float4*>(&Ob[(size_t)row * NC + ct * 16 + lg * 4]) = o;
    }
    dot += __shfl_xor(dot, 16);
    dot += __shfl_xor(dot, 32);
    if (lg == 0 && ok) score[b * N0 + row] = tanhf(dot / nrm);
  }
}

// ---------- fused top-k select + map: radix threshold, then mp assignment ----------
__global__ __launch_bounds__(1024) void k_selmap(const float* __restrict__ score,
                                                 int* __restrict__ mp, int n, int k) {
  __shared__ int hist[256];
  __shared__ int ss[257];
  __shared__ int sgc[16], stc[16];
  __shared__ int wg[16], wt[16];
  __shared__ unsigned s_pref;
  __shared__ int s_r, s_gt;
  int b = blockIdx.x, t = threadIdx.x, lane = t & 63, wid = t >> 6;
  if (t == 0) { s_pref = 0u; s_r = k; s_gt = 0; }
  __syncthreads();
  for (int pass = 0; pass < 4; ++pass) {
    int shift = 24 - pass * 8;
    if (t < 256) hist[t] = 0;
    __syncthreads();
    unsigned pref = s_pref;
    unsigned pmask = (pass == 0) ? 0u : (0xFFFFFFFFu << (shift + 8));
    for (int j0 = 0; j0 < n; j0 += 1024) {
      int j = j0 + t;
      unsigned key = (j < n) ? mono_u(score[b * N0 + j]) : 0u;
      unsigned d = (key >> shift) & 255;
      int contrib = (j < n) && ((key & pmask) == pref);
      unsigned long long bal = __ballot(contrib);
      if (bal == 0) continue;
      int fl = __ffsll((long long)bal) - 1;
      unsigned dref = __shfl(d, fl);
      if (__all(!contrib || d == dref)) {
        if (lane == fl) atomicAdd(&hist[dref], (int)__popcll(bal));
      } else if (contrib) {
        atomicAdd(&hist[d], 1);
      }
    }
    __syncthreads();
    if (t < 256) ss[t] = hist[t];
    __syncthreads();
    for (int o = 1; o < 256; o <<= 1) {
      int v = 0;
      if (t < 256) v = (t + o < 256) ? ss[t + o] : 0;
      __syncthreads();
      if (t < 256) ss[t] += v;
      __syncthreads();
    }
    int r = s_r;
    __syncthreads();
    if (t < 256) {
      int nxt = (t == 255) ? 0 : ss[t + 1];
      if (ss[t] >= r && nxt < r) {
        s_gt += nxt;
        s_r = r - nxt;
        s_pref = pref | ((unsigned)t << shift);
      }
    }
    __syncthreads();
  }
  unsigned vs = s_pref;
  int q = k - s_gt;
  {
    int g = 0, tt = 0;
    for (int it = 0; it < 16; ++it) {
      int j = wid * 1024 + it * 64 + lane;
      unsigned key = (j < n) ? mono_u(score[b * N0 + j]) : 0u;
      g += (int)__popcll(__ballot((j < n) && (key > vs)));
      tt += (int)__popcll(__ballot((j < n) && (key == vs)));
    }
    if (lane == 0) { sgc[wid] = g; stc[wid] = tt; }
  }
  __syncthreads();
  int gb = 0, tb = 0;
  for (int c = 0; c < 16; ++c) {
    int j = c * 1024 + t;
    unsigned key = (j < n) ? mono_u(score[b * N0 + j]) : 0u;
    int gt = (j < n) && (key > vs);
    int tie = (j < n) && (key == vs);
    unsigned long long bg = __ballot(gt), bt = __ballot(tie);
    if (lane == 0) { wg[wid] = (int)__popcll(bg); wt[wid] = (int)__popcll(bt); }
    __syncthreads();
    if (j < n) {
      unsigned long long ltm = (lane == 63) ? ~0ull >> 1 : ((1ull << lane) - 1);
      int gloc = (int)__popcll(bg & ltm);
      int tloc = (int)__popcll(bt & ltm);
      for (int w = 0; w < 16; w++) {
        if (w < wid) { gloc += wg[w]; tloc += wt[w]; }
      }
      int tie_rank = tb + tloc;
      int sel = gt || (tie && tie_rank < q);
      int pos = gb + gloc + min(tie_rank, q);
      mp[b * N0 + j] = sel ? pos : -1;
    }
    gb += sgc[c];
    tb += stc[c];
    __syncthreads();
  }
}

// ---------- compact (fused readout, XCD-pinned): Xa[m] = x2[node]*val (f32) ----------
__global__ __launch_bounds__(256) void k_compact(const float* __restrict__ Xin,
                                                 float* __restrict__ Xout,
                                                 const int* __restrict__ mp,
                                                 const float* __restrict__ score,
                                                 int* __restrict__ maxbuf, float* __restrict__ sumbuf,
                                                 int n) {
  __shared__ float smx[128], ssm[128];
  int b = blockIdx.x & 7;
  int base = (blockIdx.x >> 3) * 64;
  if (base >= n) return;
  int c = threadIdx.x & 127, h = threadIdx.x >> 7;
  float mx = -INFINITY, sm = 0.f;
  for (int r = h; r < 64; r += 2) {
    int node = base + r;
    if (node >= n) break;
    int m = mp[b * N0 + node];
    if (m < 0) continue;
    float val = score[b * N0 + node];
    float v = Xin[((size_t)b * N0 + node) * NC + c] * val;
    Xout[((size_t)b * N0 + m) * NC + c] = v;
    mx = fmaxf(mx, v);
    sm += v;
  }
  if (h) { smx[c] = mx; ssm[c] = sm; }
  __syncthreads();
  if (!h) {
    mx = fmaxf(mx, smx[c]);
    sm += ssm[c];
    atomicMax(&maxbuf[b * NC + c], f2ikey(mx));
    atomicAdd(&sumbuf[b * NC + c], sm);
  }
}

// ---------- remap edges in place (XCD-pinned per graph); count next-depth degrees ----------
__global__ void k_remap(int* __restrict__ srcw, int* __restrict__ dstw,
                        const int* __restrict__ mp, int* __restrict__ cnt) {
  int b = blockIdx.x & 7;
  int bi = blockIdx.x >> 3;
  int nblk = gridDim.x >> 3;
  for (int e = bi * blockDim.x + threadIdx.x; e < NE; e += nblk * blockDim.x) {
    int i = b * NE + e;
    int d = dstw[i];
    if (d < 0) continue;
    int s = srcw[i];
    int ns = mp[b * N0 + s], nd = mp[b * N0 + d];
    if (ns >= 0 && nd >= 0) {
      srcw[i] = ns;
      dstw[i] = nd;
      atomicAdd(&cnt[b * N0 + nd], 1);
    } else {
      srcw[i] = 0;
      dstw[i] = -1;
    }
  }
}

// ---------- predictor MLP (folds readout-sum across depths) ----------
__global__ __launch_bounds__(256) void k_pred(const int* __restrict__ maxbuf,
                                              const float* __restrict__ sumbuf,
                                              const float* __restrict__ q1w, const float* __restrict__ q1b,
                                              const float* __restrict__ q2w, const float* __restrict__ q2b,
                                              const float* __restrict__ q3w, const float* __restrict__ q3b,
                                              float* __restrict__ out) {
  __shared__ float rr[256], h1[128], h2[64];
  int b = blockIdx.x, t = threadIdx.x;
  const float kdiv[4] = {13108.f, 10487.f, 8390.f, 6712.f};
  float acc = 0.f;
#pragma unroll
  for (int d = 0; d < 4; d++) {
    if (t < 128) acc += ikey2f(maxbuf[d * NB * NC + b * NC + t]);
    else acc += sumbuf[d * NB * NC + b * NC + (t - 128)] / kdiv[d];
  }
  rr[t] = acc;
  __syncthreads();
  if (t < 128) {
    float s = q1b[t];
    for (int j = 0; j < 256; j++) s = fmaf(rr[j], q1w[j * 128 + t], s);
    h1[t] = fmaxf(s, 0.f);
  }
  __syncthreads();
  if (t < 64) {
    float s = q2b[t];
    for (int j = 0; j < 128; j++) s = fmaf(h1[j], q2w[j * 64 + t], s);
    h2[t] = fmaxf(s, 0.f);
  }
  __syncthreads();
  if (t < 2) {
    float s = q3b[t];
    for (int j = 0; j < 64; j++) s = fmaf(h2[j], q3w[j * 2 + t], s);
    out[b * 2 + t] = s;
  }
}

// ---------- host orchestration ----------
extern "C" void kernel_launch(void* const* d_in, const int* in_sizes, int n_in,
                              void* d_out, int out_size, void* d_ws, size_t ws_size,
                              hipStream_t stream) {
  const float* x = (const float*)d_in[0];
  const int* src = (const int*)d_in[1];
  const int* dst = (const int*)d_in[2];
  const float* q1w = (const float*)d_in[23];
  const float* q1b = (const float*)d_in[24];
  const float* q2w = (const float*)d_in[25];
  const float* q2b = (const float*)d_in[26];
  const float* q3w = (const float*)d_in[27];
  const float* q3b = (const float*)d_in[28];

  char* p = (char*)d_ws;
  auto alloc = [&](size_t bytes) {
    char* q = p;
    p += (bytes + 255) & ~(size_t)255;
    return q;
  };
  float* Xa = (float*)alloc((size_t)NB * N0 * NC * 4);       // pooled x (f32)
  float* Xb = (float*)alloc((size_t)NB * N0 * NC * 4);       // x2 (f32, gg out)
  int* srcw = (int*)alloc((size_t)NB * NE * 4);
  int* dstw = (int*)alloc((size_t)NB * NE * 4);
  int* elist = (int*)alloc((size_t)NB * NE * 4);
  int* cnt = (int*)alloc((size_t)NB * N0 * 4);
  int* offs = (int*)alloc((size_t)NB * N0 * 4);
  int* cursor = (int*)alloc((size_t)NB * N0 * 4);
  float* score = (float*)alloc((size_t)NB * N0 * 4);
  int* mp = (int*)alloc((size_t)NB * N0 * 4);
  int* maxbuf = (int*)alloc(4 * NB * NC * 4);
  float* sumbuf = (float*)alloc(4 * NB * NC * 4);
  ushort_t* Wt_all = (ushort_t*)alloc((size_t)8 * NC * NC * 2);

  hipMemsetAsync(cnt, 0, (size_t)NB * N0 * 4, stream);
  k_init<<<2048, 256, 0, stream>>>(src, dst, srcw, dstw, cnt, maxbuf, sumbuf);
  k_wprep8<<<512, 256, 0, stream>>>(
      (const float*)d_in[3], (const float*)d_in[5],
      (const float*)d_in[8], (const float*)d_in[10],
      (const float*)d_in[13], (const float*)d_in[15],
      (const float*)d_in[18], (const float*)d_in[20], Wt_all);

  static const int NSv[4] = {16384, 13108, 10487, 8390};
  static const int KSv[4] = {13108, 10487, 8390, 6712};
  for (int i = 0; i < 4; i++) {
    int n = NSv[i], k = KSv[i];
    const float* b1 = (const float*)d_in[3 + i * 5 + 1];
    const float* b2 = (const float*)d_in[3 + i * 5 + 3];
    const float* pw = (const float*)d_in[3 + i * 5 + 4];
    const ushort_t* w1t = Wt_all + (size_t)(2 * i) * NC * NC;
    const ushort_t* w2t = Wt_all + (size_t)(2 * i + 1) * NC * NC;
    const float* cur = (i == 0) ? x : Xa;

    k_scan<<<NB, 1024, 0, stream>>>(cnt, offs, cursor);
    k_fill<<<1024, 256, 0, stream>>>(srcw, dstw, cursor, elist);

    k_gg<<<((n + 127) / 128) * 8, 512, 0, stream>>>(cur, offs, cursor, elist,
                                                    w1t, b1, w2t, b2, pw, Xb, score, n);

    k_selmap<<<NB, 1024, 0, stream>>>(score, mp, n, k);

    k_compact<<<((n + 63) / 64) * 8, 256, 0, stream>>>(Xb, Xa, mp, score,
                                                       maxbuf + i * NB * NC, sumbuf + i * NB * NC, n);
    k_remap<<<512, 256, 0, stream>>>(srcw, dstw, mp, cnt);
  }

  k_pred<<<NB, 256, 0, stream>>>(maxbuf, sumbuf, q1w, q1b, q2w, q2b, q3w, q3b, (float*)d_out);
}

// Round 18
// 732.698 us; speedup vs baseline: 1.2492x; 1.2492x over previous
//
#include <hip/hip_runtime.h>
#include <math.h>

#define NB 8
#define N0 16384
#define NC 128
#define NE 98304

typedef unsigned short ushort_t;
using short8 = __attribute__((ext_vector_type(8))) short;
using f32x4 = __attribute__((ext_vector_type(4))) float;

// ---------- helpers ----------
__device__ __forceinline__ unsigned mono_u(float f) {
  unsigned u = __float_as_uint(f);
  return (u & 0x80000000u) ? ~u : (u | 0x80000000u);
}
__device__ __forceinline__ int f2ikey(float f) {
  int i = __float_as_int(f);
  return (i >= 0) ? i : (i ^ 0x7fffffff);
}
__device__ __forceinline__ float ikey2f(int k) {
  return __int_as_float(k >= 0 ? k : (k ^ 0x7fffffff));
}
__device__ __forceinline__ ushort_t f2bf_rne(float f) {
  unsigned u = __float_as_uint(f);
  unsigned r = u + 0x7fffu + ((u >> 16) & 1u);
  return (ushort_t)(r >> 16);
}
__device__ __forceinline__ int wscan_incl(int v, int lane) {
#pragma unroll
  for (int o = 1; o < 64; o <<= 1) {
    int u = __shfl_up(v, o);
    if (lane >= o) v += u;
  }
  return v;
}

// ---------- init: edges copy + depth-0 degree count, readout bufs ----------
// cnt must be pre-zeroed.
__global__ void k_init(const int* __restrict__ src, const int* __restrict__ dst,
                       int* __restrict__ srcw, int* __restrict__ dstw,
                       int* __restrict__ cnt, int* __restrict__ maxbuf, float* __restrict__ sumbuf) {
  int stride = gridDim.x * blockDim.x;
  int i = blockIdx.x * blockDim.x + threadIdx.x;
  for (int j = i; j < NB * NE; j += stride) {
    int d = dst[j];
    srcw[j] = src[j];
    dstw[j] = d;
    atomicAdd(&cnt[(j / NE) * N0 + d], 1);
  }
  for (int j = i; j < 4 * NB * NC; j += stride) {
    maxbuf[j] = (int)0x80000000;
    sumbuf[j] = 0.f;
  }
}

// ---------- weight prep: W[k][c] f32 -> Wt[c][k] bf16 ----------
__global__ void k_wprep(const float* __restrict__ W, ushort_t* __restrict__ Wt) {
  int id = blockIdx.x * blockDim.x + threadIdx.x;
  if (id >= NC * NC) return;
  int k = id >> 7, c = id & 127;
  Wt[c * NC + k] = f2bf_rne(W[id]);
}

// ---------- CSR build: per-graph exclusive scan (wave-shuffle); zeroes cnt ----------
__global__ __launch_bounds__(1024) void k_scan(int* __restrict__ cnt,
                                               int* __restrict__ offs, int* __restrict__ cursor) {
  __shared__ int wsum[16];
  int b = blockIdx.x, t = threadIdx.x, lane = t & 63, wid = t >> 6;
  int base = b * N0 + t * 16;
  int loc[16];
  int s = 0;
#pragma unroll
  for (int j = 0; j < 16; j++) { loc[j] = cnt[base + j]; s += loc[j]; cnt[base + j] = 0; }
  int incl = wscan_incl(s, lane);
  if (lane == 63) wsum[wid] = incl;
  __syncthreads();
  int woff = 0;
  for (int w = 0; w < wid; w++) woff += wsum[w];
  int excl = woff + incl - s;
#pragma unroll
  for (int j = 0; j < 16; j++) {
    offs[base + j] = excl;
    cursor[base + j] = excl;
    excl += loc[j];
  }
}

// ---------- CSR build: fill edge list; cursor ends as end-offset ----------
// NOTE: atomic placement order determines elist order -> summation order.
// Do NOT change this kernel's launch shape (numerics-sensitive downstream).
__global__ void k_fill(const int* __restrict__ srcw, const int* __restrict__ dstw,
                       int* __restrict__ cursor, int* __restrict__ elist) {
  int tot = NB * NE;
  for (int i = blockIdx.x * blockDim.x + threadIdx.x; i < tot; i += gridDim.x * blockDim.x) {
    int d = dstw[i];
    if (d < 0) continue;
    int b = i / NE;
    int pos = atomicAdd(&cursor[b * N0 + d], 1);
    elist[b * NE + pos] = srcw[i];
  }
}

// ---------- gather (f32 in, bf16 out): H[node] = bf16( X[node] + sum_{src} X[src] ) ----------
// 1D grid, graph = blockIdx.x & 7 (XCD-pinned). Half-waves, 2 edges per wave-load.
// Round-9 verbatim: summation order is numerics-sensitive, do not restructure.
__global__ void k_gather(const float* __restrict__ X, ushort_t* __restrict__ H,
                         const int* __restrict__ offs, const int* __restrict__ cend,
                         const int* __restrict__ elist, int n) {
  int b = blockIdx.x & 7;
  int chunk = blockIdx.x >> 3;
  int lane = threadIdx.x & 63, wid = threadIdx.x >> 6;
  int node = chunk * 4 + wid;
  if (node >= n) return;
  int off = offs[b * N0 + node];
  int deg = cend[b * N0 + node] - off;
  int h = lane >> 5, c4 = lane & 31;
  const float* Xb = X + (size_t)b * N0 * NC;

  float4 acc0 = make_float4(0.f, 0.f, 0.f, 0.f);
  float4 acc1 = make_float4(0.f, 0.f, 0.f, 0.f);
  if (h == 0) acc0 = *reinterpret_cast<const float4*>(&Xb[(size_t)node * NC + c4 * 4]);

  for (int base = 0; base < deg; base += 64) {
    int m = min(64, deg - base);
    int eid = (lane < m) ? elist[b * NE + off + base + lane] : 0;
    int j = 0;
    for (; j + 4 <= m; j += 4) {
      int s0 = __shfl(eid, j + h);
      int s1 = __shfl(eid, j + 2 + h);
      float4 v0 = *reinterpret_cast<const float4*>(&Xb[(size_t)s0 * NC + c4 * 4]);
      float4 v1 = *reinterpret_cast<const float4*>(&Xb[(size_t)s1 * NC + c4 * 4]);
      acc0.x += v0.x; acc0.y += v0.y; acc0.z += v0.z; acc0.w += v0.w;
      acc1.x += v1.x; acc1.y += v1.y; acc1.z += v1.z; acc1.w += v1.w;
    }
    if (j + 2 <= m) {
      int s0 = __shfl(eid, j + h);
      float4 v0 = *reinterpret_cast<const float4*>(&Xb[(size_t)s0 * NC + c4 * 4]);
      acc0.x += v0.x; acc0.y += v0.y; acc0.z += v0.z; acc0.w += v0.w;
      j += 2;
    }
    if (j < m) {
      int s0 = __shfl(eid, j);
      if (h == 0) {
        float4 v0 = *reinterpret_cast<const float4*>(&Xb[(size_t)s0 * NC + c4 * 4]);
        acc0.x += v0.x; acc0.y += v0.y; acc0.z += v0.z; acc0.w += v0.w;
      }
    }
  }
  acc0.x += acc1.x; acc0.y += acc1.y; acc0.z += acc1.z; acc0.w += acc1.w;
  acc0.x += __shfl_xor(acc0.x, 32);
  acc0.y += __shfl_xor(acc0.y, 32);
  acc0.z += __shfl_xor(acc0.z, 32);
  acc0.w += __shfl_xor(acc0.w, 32);
  if (h == 0) {
    unsigned p0 = (unsigned)f2bf_rne(acc0.x) | ((unsigned)f2bf_rne(acc0.y) << 16);
    unsigned p1 = (unsigned)f2bf_rne(acc0.z) | ((unsigned)f2bf_rne(acc0.w) << 16);
    *reinterpret_cast<uint2*>(&H[((size_t)b * N0 + node) * NC + c4 * 4]) = make_uint2(p0, p1);
  }
}

// ---------- fused GIN MLP: x2 = relu(relu(h0@W1+b1)@W2+b2), fused score ----------
// Swapped mfma operands (D: lane=X-row, regs=4 W-cols -> float4 stores); W in LDS.
__global__ __launch_bounds__(256) void k_gin(const ushort_t* __restrict__ Xh,
                                             float* __restrict__ Xout,
                                             const ushort_t* __restrict__ W1t,
                                             const float* __restrict__ b1,
                                             const ushort_t* __restrict__ W2t,
                                             const float* __restrict__ b2,
                                             const float* __restrict__ pw,
                                             float* __restrict__ score, int n) {
  __shared__ ushort_t Ts[128 * 136];
  __shared__ ushort_t Wsh[128 * 136];
  int b = blockIdx.x & 7;
  int r0 = (blockIdx.x >> 3) * 128;
  int t = threadIdx.x;
  const ushort_t* Xg = Xh + (size_t)b * N0 * NC;

#pragma unroll
  for (int p = 0; p < 8; p++) {
    int id = t + p * 256;
    int row = id >> 4, seg = id & 15;
    short8 vh = (short8)0;
    if (r0 + row < n)
      vh = *reinterpret_cast<const short8*>(&Xg[(size_t)(r0 + row) * NC + seg * 8]);
    *reinterpret_cast<short8*>(&Ts[row * 136 + seg * 8]) = vh;
    *reinterpret_cast<short8*>(&Wsh[row * 136 + seg * 8]) =
        *reinterpret_cast<const short8*>(&W1t[row * NC + seg * 8]);
  }
  __syncthreads();

  int lane = t & 63, w = t >> 6;
  int li = lane & 15, lg = lane >> 4;
  int rbase = w * 32;

  f32x4 acc[2][8];
#pragma unroll
  for (int rt = 0; rt < 2; rt++)
#pragma unroll
    for (int ct = 0; ct < 8; ct++) acc[rt][ct] = (f32x4)0.f;

#pragma unroll
  for (int ks = 0; ks < 4; ks++) {
    short8 x0 = *reinterpret_cast<const short8*>(&Ts[(rbase + li) * 136 + ks * 32 + lg * 8]);
    short8 x1 = *reinterpret_cast<const short8*>(&Ts[(rbase + 16 + li) * 136 + ks * 32 + lg * 8]);
#pragma unroll
    for (int ct = 0; ct < 8; ct++) {
      short8 wf = *reinterpret_cast<const short8*>(&Wsh[(ct * 16 + li) * 136 + ks * 32 + lg * 8]);
      acc[0][ct] = __builtin_amdgcn_mfma_f32_16x16x32_bf16(wf, x0, acc[0][ct], 0, 0, 0);
      acc[1][ct] = __builtin_amdgcn_mfma_f32_16x16x32_bf16(wf, x1, acc[1][ct], 0, 0, 0);
    }
  }

#pragma unroll
  for (int rt = 0; rt < 2; rt++) {
    int row = rbase + rt * 16 + li;
#pragma unroll
    for (int ct = 0; ct < 8; ct++) {
      float4 bq = *reinterpret_cast<const float4*>(&b1[ct * 16 + lg * 4]);
      float o0 = fmaxf(acc[rt][ct][0] + bq.x, 0.f);
      float o1 = fmaxf(acc[rt][ct][1] + bq.y, 0.f);
      float o2 = fmaxf(acc[rt][ct][2] + bq.z, 0.f);
      float o3 = fmaxf(acc[rt][ct][3] + bq.w, 0.f);
      unsigned p0 = (unsigned)f2bf_rne(o0) | ((unsigned)f2bf_rne(o1) << 16);
      unsigned p1 = (unsigned)f2bf_rne(o2) | ((unsigned)f2bf_rne(o3) << 16);
      *reinterpret_cast<uint2*>(&Ts[row * 136 + ct * 16 + lg * 4]) = make_uint2(p0, p1);
    }
  }

  __syncthreads();
#pragma unroll
  for (int p = 0; p < 8; p++) {
    int id = t + p * 256;
    int row = id >> 4, seg = id & 15;
    *reinterpret_cast<short8*>(&Wsh[row * 136 + seg * 8]) =
        *reinterpret_cast<const short8*>(&W2t[row * NC + seg * 8]);
  }
  __syncthreads();

#pragma unroll
  for (int rt = 0; rt < 2; rt++)
#pragma unroll
    for (int ct = 0; ct < 8; ct++) acc[rt][ct] = (f32x4)0.f;

#pragma unroll
  for (int ks = 0; ks < 4; ks++) {
    short8 x0 = *reinterpret_cast<const short8*>(&Ts[(rbase + li) * 136 + ks * 32 + lg * 8]);
    short8 x1 = *reinterpret_cast<const short8*>(&Ts[(rbase + 16 + li) * 136 + ks * 32 + lg * 8]);
#pragma unroll
    for (int ct = 0; ct < 8; ct++) {
      short8 wf = *reinterpret_cast<const short8*>(&Wsh[(ct * 16 + li) * 136 + ks * 32 + lg * 8]);
      acc[0][ct] = __builtin_amdgcn_mfma_f32_16x16x32_bf16(wf, x0, acc[0][ct], 0, 0, 0);
      acc[1][ct] = __builtin_amdgcn_mfma_f32_16x16x32_bf16(wf, x1, acc[1][ct], 0, 0, 0);
    }
  }

  f32x4 pq[8];
  float psum = 0.f;
#pragma unroll
  for (int ct = 0; ct < 8; ct++) {
    pq[ct] = *reinterpret_cast<const f32x4*>(&pw[ct * 16 + lg * 4]);
    psum = fmaf(pq[ct][0], pq[ct][0], psum);
    psum = fmaf(pq[ct][1], pq[ct][1], psum);
    psum = fmaf(pq[ct][2], pq[ct][2], psum);
    psum = fmaf(pq[ct][3], pq[ct][3], psum);
  }
  psum += __shfl_xor(psum, 16);
  psum += __shfl_xor(psum, 32);
  float nrm = sqrtf(psum);

  float* Ob = Xout + (size_t)b * N0 * NC;
#pragma unroll
  for (int rt = 0; rt < 2; rt++) {
    int row = r0 + rbase + rt * 16 + li;
    bool ok = row < n;
    float dot = 0.f;
#pragma unroll
    for (int ct = 0; ct < 8; ct++) {
      float4 bq = *reinterpret_cast<const float4*>(&b2[ct * 16 + lg * 4]);
      float4 o;
      o.x = fmaxf(acc[rt][ct][0] + bq.x, 0.f);
      o.y = fmaxf(acc[rt][ct][1] + bq.y, 0.f);
      o.z = fmaxf(acc[rt][ct][2] + bq.z, 0.f);
      o.w = fmaxf(acc[rt][ct][3] + bq.w, 0.f);
      dot = fmaf(o.x, pq[ct][0], dot);
      dot = fmaf(o.y, pq[ct][1], dot);
      dot = fmaf(o.z, pq[ct][2], dot);
      dot = fmaf(o.w, pq[ct][3], dot);
      if (ok) *reinterpret_cast<float4*>(&Ob[(size_t)row * NC + ct * 16 + lg * 4]) = o;
    }
    dot += __shfl_xor(dot, 16);
    dot += __shfl_xor(dot, 32);
    if (lg == 0 && ok) score[b * N0 + row] = tanhf(dot / nrm);
  }
}

// ---------- top-k threshold via 4-pass radix select (parallel digit scan) ----------
__global__ __launch_bounds__(1024) void k_select(const float* __restrict__ score,
                                                 unsigned* __restrict__ vstar, int* __restrict__ quota,
                                                 int* __restrict__ gcnt, int* __restrict__ tcnt,
                                                 int n, int k) {
  __shared__ int hist[256];
  __shared__ int ss[257];
  __shared__ unsigned s_pref;
  __shared__ int s_r, s_gt;
  int b = blockIdx.x, t = threadIdx.x, lane = t & 63;
  if (t == 0) { s_pref = 0u; s_r = k; s_gt = 0; }
  __syncthreads();
  for (int pass = 0; pass < 4; ++pass) {
    int shift = 24 - pass * 8;
    if (t < 256) hist[t] = 0;
    __syncthreads();
    unsigned pref = s_pref;
    unsigned pmask = (pass == 0) ? 0u : (0xFFFFFFFFu << (shift + 8));
    for (int j0 = 0; j0 < n; j0 += 1024) {
      int j = j0 + t;
      unsigned key = (j < n) ? mono_u(score[b * N0 + j]) : 0u;
      unsigned d = (key >> shift) & 255;
      int contrib = (j < n) && ((key & pmask) == pref);
      unsigned long long bal = __ballot(contrib);
      if (bal == 0) continue;
      int fl = __ffsll((long long)bal) - 1;
      unsigned dref = __shfl(d, fl);
      if (__all(!contrib || d == dref)) {
        if (lane == fl) atomicAdd(&hist[dref], (int)__popcll(bal));
      } else if (contrib) {
        atomicAdd(&hist[d], 1);
      }
    }
    __syncthreads();
    if (t < 256) ss[t] = hist[t];
    __syncthreads();
    for (int o = 1; o < 256; o <<= 1) {
      int v = 0;
      if (t < 256) v = (t + o < 256) ? ss[t + o] : 0;
      __syncthreads();
      if (t < 256) ss[t] += v;
      __syncthreads();
    }
    int r = s_r;
    __syncthreads();
    if (t < 256) {
      int nxt = (t == 255) ? 0 : ss[t + 1];
      if (ss[t] >= r && nxt < r) {
        s_gt += nxt;
        s_r = r - nxt;
        s_pref = pref | ((unsigned)t << shift);
      }
    }
    __syncthreads();
  }
  if (t == 0) {
    vstar[b] = s_pref;
    quota[b] = k - s_gt;
  }
  __syncthreads();
  unsigned vs = s_pref;
  int w = t >> 6;
  int g = 0, tt = 0;
  for (int it = 0; it < 16; ++it) {
    int j = w * 1024 + it * 64 + lane;
    unsigned key = (j < n) ? mono_u(score[b * N0 + j]) : 0u;
    g += (int)__popcll(__ballot((j < n) && (key > vs)));
    tt += (int)__popcll(__ballot((j < n) && (key == vs)));
  }
  if (lane == 0) { gcnt[b * 16 + w] = g; tcnt[b * 16 + w] = tt; }
}

// ---------- map: assign new ids, jax.lax.top_k tie semantics ----------
__global__ __launch_bounds__(1024) void k_map_wr(const float* __restrict__ score,
                                                 const unsigned* __restrict__ vstar,
                                                 const int* __restrict__ quota,
                                                 const int* __restrict__ gcnt, const int* __restrict__ tcnt,
                                                 int* __restrict__ mp, int n) {
  __shared__ int wg[16], wt[16];
  __shared__ int s_gb, s_tb;
  int b = blockIdx.y, chunk = blockIdx.x, t = threadIdx.x;
  int lane = t & 63, wid = t >> 6;
  if (t == 0) {
    int gb = 0, tb = 0;
    for (int c = 0; c < chunk; c++) { gb += gcnt[b * 16 + c]; tb += tcnt[b * 16 + c]; }
    s_gb = gb; s_tb = tb;
  }
  int j = chunk * 1024 + t;
  unsigned vs = vstar[b];
  int q = quota[b];
  unsigned key = (j < n) ? mono_u(score[b * N0 + j]) : 0u;
  int gt = (j < n) && (key > vs);
  int tie = (j < n) && (key == vs);
  unsigned long long bg = __ballot(gt), bt = __ballot(tie);
  if (lane == 0) { wg[wid] = (int)__popcll(bg); wt[wid] = (int)__popcll(bt); }
  __syncthreads();
  if (j >= n) return;
  unsigned long long ltm = (lane == 63) ? ~0ull >> 1 : ((1ull << lane) - 1);
  int gloc = (int)__popcll(bg & ltm);
  int tloc = (int)__popcll(bt & ltm);
  for (int w = 0; w < 16; w++) {
    if (w < wid) { gloc += wg[w]; tloc += wt[w]; }
  }
  int tie_rank = s_tb + tloc;
  int sel = gt || (tie && tie_rank < q);
  int pos = s_gb + gloc + min(tie_rank, q);
  mp[b * N0 + j] = sel ? pos : -1;
}

// ---------- compact (fused readout, XCD-pinned): Xa[m] = x2[node]*val (f32) ----------
__global__ __launch_bounds__(256) void k_compact(const float* __restrict__ Xin,
                                                 float* __restrict__ Xout,
                                                 const int* __restrict__ mp,
                                                 const float* __restrict__ score,
                                                 int* __restrict__ maxbuf, float* __restrict__ sumbuf,
                                                 int n) {
  __shared__ float smx[128], ssm[128];
  int b = blockIdx.x & 7;
  int base = (blockIdx.x >> 3) * 64;
  if (base >= n) return;
  int c = threadIdx.x & 127, h = threadIdx.x >> 7;
  float mx = -INFINITY, sm = 0.f;
  for (int r = h; r < 64; r += 2) {
    int node = base + r;
    if (node >= n) break;
    int m = mp[b * N0 + node];
    if (m < 0) continue;
    float val = score[b * N0 + node];
    float v = Xin[((size_t)b * N0 + node) * NC + c] * val;
    Xout[((size_t)b * N0 + m) * NC + c] = v;
    mx = fmaxf(mx, v);
    sm += v;
  }
  if (h) { smx[c] = mx; ssm[c] = sm; }
  __syncthreads();
  if (!h) {
    mx = fmaxf(mx, smx[c]);
    sm += ssm[c];
    atomicMax(&maxbuf[b * NC + c], f2ikey(mx));
    atomicAdd(&sumbuf[b * NC + c], sm);
  }
}

// ---------- remap edges in place (XCD-pinned per graph); count next-depth degrees ----------
__global__ void k_remap(int* __restrict__ srcw, int* __restrict__ dstw,
                        const int* __restrict__ mp, int* __restrict__ cnt) {
  int b = blockIdx.x & 7;
  int bi = blockIdx.x >> 3;
  int nblk = gridDim.x >> 3;
  for (int e = bi * blockDim.x + threadIdx.x; e < NE; e += nblk * blockDim.x) {
    int i = b * NE + e;
    int d = dstw[i];
    if (d < 0) continue;
    int s = srcw[i];
    int ns = mp[b * N0 + s], nd = mp[b * N0 + d];
    if (ns >= 0 && nd >= 0) {
      srcw[i] = ns;
      dstw[i] = nd;
      atomicAdd(&cnt[b * N0 + nd], 1);
    } else {
      srcw[i] = 0;
      dstw[i] = -1;
    }
  }
}

// ---------- predictor MLP (folds readout-sum across depths) ----------
__global__ __launch_bounds__(256) void k_pred(const int* __restrict__ maxbuf,
                                              const float* __restrict__ sumbuf,
                                              const float* __restrict__ q1w, const float* __restrict__ q1b,
                                              const float* __restrict__ q2w, const float* __restrict__ q2b,
                                              const float* __restrict__ q3w, const float* __restrict__ q3b,
                                              float* __restrict__ out) {
  __shared__ float rr[256], h1[128], h2[64];
  int b = blockIdx.x, t = threadIdx.x;
  const float kdiv[4] = {13108.f, 10487.f, 8390.f, 6712.f};
  float acc = 0.f;
#pragma unroll
  for (int d = 0; d < 4; d++) {
    if (t < 128) acc += ikey2f(maxbuf[d * NB * NC + b * NC + t]);
    else acc += sumbuf[d * NB * NC + b * NC + (t - 128)] / kdiv[d];
  }
  rr[t] = acc;
  __syncthreads();
  if (t < 128) {
    float s = q1b[t];
    for (int j = 0; j < 256; j++) s = fmaf(rr[j], q1w[j * 128 + t], s);
    h1[t] = fmaxf(s, 0.f);
  }
  __syncthreads();
  if (t < 64) {
    float s = q2b[t];
    for (int j = 0; j < 128; j++) s = fmaf(h1[j], q2w[j * 64 + t], s);
    h2[t] = fmaxf(s, 0.f);
  }
  __syncthreads();
  if (t < 2) {
    float s = q3b[t];
    for (int j = 0; j < 64; j++) s = fmaf(h2[j], q3w[j * 2 + t], s);
    out[b * 2 + t] = s;
  }
}

// ---------- host orchestration ----------
extern "C" void kernel_launch(void* const* d_in, const int* in_sizes, int n_in,
                              void* d_out, int out_size, void* d_ws, size_t ws_size,
                              hipStream_t stream) {
  const float* x = (const float*)d_in[0];
  const int* src = (const int*)d_in[1];
  const int* dst = (const int*)d_in[2];
  const float* q1w = (const float*)d_in[23];
  const float* q1b = (const float*)d_in[24];
  const float* q2w = (const float*)d_in[25];
  const float* q2b = (const float*)d_in[26];
  const float* q3w = (const float*)d_in[27];
  const float* q3b = (const float*)d_in[28];

  char* p = (char*)d_ws;
  auto alloc = [&](size_t bytes) {
    char* q = p;
    p += (bytes + 255) & ~(size_t)255;
    return q;
  };
  float* Xa = (float*)alloc((size_t)NB * N0 * NC * 4);       // pooled x (f32)
  float* Xb = (float*)alloc((size_t)NB * N0 * NC * 4);       // x2 (f32, gin out)
  ushort_t* Xh = (ushort_t*)alloc((size_t)NB * N0 * NC * 2); // h0 (bf16)
  int* srcw = (int*)alloc((size_t)NB * NE * 4);
  int* dstw = (int*)alloc((size_t)NB * NE * 4);
  int* elist = (int*)alloc((size_t)NB * NE * 4);
  int* cnt = (int*)alloc((size_t)NB * N0 * 4);
  int* offs = (int*)alloc((size_t)NB * N0 * 4);
  int* cursor = (int*)alloc((size_t)NB * N0 * 4);
  float* score = (float*)alloc((size_t)NB * N0 * 4);
  int* mp = (int*)alloc((size_t)NB * N0 * 4);
  unsigned* vstar = (unsigned*)alloc(256);
  int* quota = (int*)alloc(256);
  int* gcnt = (int*)alloc(NB * 16 * 4);
  int* tcnt = (int*)alloc(NB * 16 * 4);
  int* maxbuf = (int*)alloc(4 * NB * NC * 4);
  float* sumbuf = (float*)alloc(4 * NB * NC * 4);
  ushort_t* Wt_all = (ushort_t*)alloc((size_t)8 * NC * NC * 2);

  hipMemsetAsync(cnt, 0, (size_t)NB * N0 * 4, stream);
  k_init<<<2048, 256, 0, stream>>>(src, dst, srcw, dstw, cnt, maxbuf, sumbuf);
  for (int i = 0; i < 4; i++) {
    k_wprep<<<64, 256, 0, stream>>>((const float*)d_in[3 + i * 5 + 0], Wt_all + (size_t)(2 * i) * NC * NC);
    k_wprep<<<64, 256, 0, stream>>>((const float*)d_in[3 + i * 5 + 2], Wt_all + (size_t)(2 * i + 1) * NC * NC);
  }

  static const int NSv[4] = {16384, 13108, 10487, 8390};
  static const int KSv[4] = {13108, 10487, 8390, 6712};
  for (int i = 0; i < 4; i++) {
    int n = NSv[i], k = KSv[i];
    const float* b1 = (const float*)d_in[3 + i * 5 + 1];
    const float* b2 = (const float*)d_in[3 + i * 5 + 3];
    const float* pw = (const float*)d_in[3 + i * 5 + 4];
    const ushort_t* w1t = Wt_all + (size_t)(2 * i) * NC * NC;
    const ushort_t* w2t = Wt_all + (size_t)(2 * i + 1) * NC * NC;
    const float* cur = (i == 0) ? x : Xa;

    k_scan<<<NB, 1024, 0, stream>>>(cnt, offs, cursor);
    k_fill<<<1024, 256, 0, stream>>>(srcw, dstw, cursor, elist);

    k_gather<<<((n + 3) / 4) * 8, 256, 0, stream>>>(cur, Xh, offs, cursor, elist, n);

    k_gin<<<((n + 127) / 128) * 8, 256, 0, stream>>>(Xh, Xb, w1t, b1, w2t, b2, pw, score, n);

    k_select<<<NB, 1024, 0, stream>>>(score, vstar, quota, gcnt, tcnt, n, k);
    dim3 gm(16, NB);
    k_map_wr<<<gm, 1024, 0, stream>>>(score, vstar, quota, gcnt, tcnt, mp, n);

    k_compact<<<((n + 63) / 64) * 8, 256, 0, stream>>>(Xb, Xa, mp, score,
                                                       maxbuf + i * NB * NC, sumbuf + i * NB * NC, n);
    k_remap<<<512, 256, 0, stream>>>(srcw, dstw, mp, cnt);
  }

  k_pred<<<NB, 256, 0, stream>>>(maxbuf, sumbuf, q1w, q1b, q2w, q2b, q3w, q3b, (float*)d_out);
}

// Round 19
// 722.685 us; speedup vs baseline: 1.2665x; 1.0139x over previous
//
#include <hip/hip_runtime.h>
#include <math.h>

#define NB 8
#define N0 16384
#define NC 128
#define NE 98304

typedef unsigned short ushort_t;
using short8 = __attribute__((ext_vector_type(8))) short;
using f32x4 = __attribute__((ext_vector_type(4))) float;

// ---------- helpers ----------
__device__ __forceinline__ unsigned mono_u(float f) {
  unsigned u = __float_as_uint(f);
  return (u & 0x80000000u) ? ~u : (u | 0x80000000u);
}
__device__ __forceinline__ int f2ikey(float f) {
  int i = __float_as_int(f);
  return (i >= 0) ? i : (i ^ 0x7fffffff);
}
__device__ __forceinline__ float ikey2f(int k) {
  return __int_as_float(k >= 0 ? k : (k ^ 0x7fffffff));
}
__device__ __forceinline__ ushort_t f2bf_rne(float f) {
  unsigned u = __float_as_uint(f);
  unsigned r = u + 0x7fffu + ((u >> 16) & 1u);
  return (ushort_t)(r >> 16);
}
__device__ __forceinline__ int wscan_incl(int v, int lane) {
#pragma unroll
  for (int o = 1; o < 64; o <<= 1) {
    int u = __shfl_up(v, o);
    if (lane >= o) v += u;
  }
  return v;
}

// ---------- init: edges copy + depth-0 degree count, readout bufs ----------
// cnt must be pre-zeroed.
__global__ void k_init(const int* __restrict__ src, const int* __restrict__ dst,
                       int* __restrict__ srcw, int* __restrict__ dstw,
                       int* __restrict__ cnt, int* __restrict__ maxbuf, float* __restrict__ sumbuf) {
  int stride = gridDim.x * blockDim.x;
  int i = blockIdx.x * blockDim.x + threadIdx.x;
  for (int j = i; j < NB * NE; j += stride) {
    int d = dst[j];
    srcw[j] = src[j];
    dstw[j] = d;
    atomicAdd(&cnt[(j / NE) * N0 + d], 1);
  }
  for (int j = i; j < 4 * NB * NC; j += stride) {
    maxbuf[j] = (int)0x80000000;
    sumbuf[j] = 0.f;
  }
}

// ---------- weight prep: W[k][c] f32 -> Wt[c][k] bf16 ----------
__global__ void k_wprep(const float* __restrict__ W, ushort_t* __restrict__ Wt) {
  int id = blockIdx.x * blockDim.x + threadIdx.x;
  if (id >= NC * NC) return;
  int k = id >> 7, c = id & 127;
  Wt[c * NC + k] = f2bf_rne(W[id]);
}

// ---------- CSR build: per-graph exclusive scan (wave-shuffle); zeroes cnt ----------
__global__ __launch_bounds__(1024) void k_scan(int* __restrict__ cnt,
                                               int* __restrict__ offs, int* __restrict__ cursor) {
  __shared__ int wsum[16];
  int b = blockIdx.x, t = threadIdx.x, lane = t & 63, wid = t >> 6;
  int base = b * N0 + t * 16;
  int loc[16];
  int s = 0;
#pragma unroll
  for (int j = 0; j < 16; j++) { loc[j] = cnt[base + j]; s += loc[j]; cnt[base + j] = 0; }
  int incl = wscan_incl(s, lane);
  if (lane == 63) wsum[wid] = incl;
  __syncthreads();
  int woff = 0;
  for (int w = 0; w < wid; w++) woff += wsum[w];
  int excl = woff + incl - s;
#pragma unroll
  for (int j = 0; j < 16; j++) {
    offs[base + j] = excl;
    cursor[base + j] = excl;
    excl += loc[j];
  }
}

// ---------- CSR build: fill edge list; cursor ends as end-offset ----------
// NOTE: atomic placement order determines elist order -> summation order.
// Do NOT change this kernel's launch shape (numerics-sensitive downstream).
__global__ void k_fill(const int* __restrict__ srcw, const int* __restrict__ dstw,
                       int* __restrict__ cursor, int* __restrict__ elist) {
  int tot = NB * NE;
  for (int i = blockIdx.x * blockDim.x + threadIdx.x; i < tot; i += gridDim.x * blockDim.x) {
    int d = dstw[i];
    if (d < 0) continue;
    int b = i / NE;
    int pos = atomicAdd(&cursor[b * N0 + d], 1);
    elist[b * NE + pos] = srcw[i];
  }
}

// ---------- gather (f32 in, bf16 out), 2 nodes per wave for ILP ----------
// Per-node arithmetic is the round-9 body VERBATIM (same chain split, same
// tail handling, same reduce order) -> bit-identical h0. Only the node->wave
// assignment changed (numerics-neutral). 4 independent load chains per wave.
__global__ void k_gather(const float* __restrict__ X, ushort_t* __restrict__ H,
                         const int* __restrict__ offs, const int* __restrict__ cend,
                         const int* __restrict__ elist, int n) {
  int b = blockIdx.x & 7;
  int chunk = blockIdx.x >> 3;
  int lane = threadIdx.x & 63, wid = threadIdx.x >> 6;
  int nodeA = chunk * 8 + wid * 2;
  if (nodeA >= n) return;
  int nodeB = nodeA + 1;
  bool hasB = (nodeB < n);
  int offA = offs[b * N0 + nodeA];
  int degA = cend[b * N0 + nodeA] - offA;
  int offB = 0, degB = 0;
  if (hasB) {
    offB = offs[b * N0 + nodeB];
    degB = cend[b * N0 + nodeB] - offB;
  }
  int h = lane >> 5, c4 = lane & 31;
  const float* Xb = X + (size_t)b * N0 * NC;

  float4 aA0 = make_float4(0.f, 0.f, 0.f, 0.f);
  float4 aA1 = make_float4(0.f, 0.f, 0.f, 0.f);
  float4 aB0 = make_float4(0.f, 0.f, 0.f, 0.f);
  float4 aB1 = make_float4(0.f, 0.f, 0.f, 0.f);
  if (h == 0) {
    aA0 = *reinterpret_cast<const float4*>(&Xb[(size_t)nodeA * NC + c4 * 4]);
    if (hasB)
      aB0 = *reinterpret_cast<const float4*>(&Xb[(size_t)nodeB * NC + c4 * 4]);
  }

  int baseA = 0, baseB = 0;
  while (baseA < degA || baseB < degB) {
    int mA = (baseA < degA) ? min(64, degA - baseA) : 0;
    int mB = (baseB < degB) ? min(64, degB - baseB) : 0;
    int eidA = (lane < mA) ? elist[b * NE + offA + baseA + lane] : 0;
    int eidB = (lane < mB) ? elist[b * NE + offB + baseB + lane] : 0;
    int jm = max(mA, mB);
    for (int j = 0; j < jm; j += 4) {
      // ---- node A (original quad/pair/single structure) ----
      if (j + 4 <= mA) {
        int s0 = __shfl(eidA, j + h);
        int s1 = __shfl(eidA, j + 2 + h);
        float4 v0 = *reinterpret_cast<const float4*>(&Xb[(size_t)s0 * NC + c4 * 4]);
        float4 v1 = *reinterpret_cast<const float4*>(&Xb[(size_t)s1 * NC + c4 * 4]);
        aA0.x += v0.x; aA0.y += v0.y; aA0.z += v0.z; aA0.w += v0.w;
        aA1.x += v1.x; aA1.y += v1.y; aA1.z += v1.z; aA1.w += v1.w;
      } else if (j < mA) {
        int rem = mA - j;
        if (rem >= 2) {
          int s0 = __shfl(eidA, j + h);
          float4 v0 = *reinterpret_cast<const float4*>(&Xb[(size_t)s0 * NC + c4 * 4]);
          aA0.x += v0.x; aA0.y += v0.y; aA0.z += v0.z; aA0.w += v0.w;
          if (rem == 3) {
            int s2 = __shfl(eidA, j + 2);
            if (h == 0) {
              float4 v2 = *reinterpret_cast<const float4*>(&Xb[(size_t)s2 * NC + c4 * 4]);
              aA0.x += v2.x; aA0.y += v2.y; aA0.z += v2.z; aA0.w += v2.w;
            }
          }
        } else {
          int s0 = __shfl(eidA, j);
          if (h == 0) {
            float4 v0 = *reinterpret_cast<const float4*>(&Xb[(size_t)s0 * NC + c4 * 4]);
            aA0.x += v0.x; aA0.y += v0.y; aA0.z += v0.z; aA0.w += v0.w;
          }
        }
      }
      // ---- node B (identical structure) ----
      if (j + 4 <= mB) {
        int s0 = __shfl(eidB, j + h);
        int s1 = __shfl(eidB, j + 2 + h);
        float4 v0 = *reinterpret_cast<const float4*>(&Xb[(size_t)s0 * NC + c4 * 4]);
        float4 v1 = *reinterpret_cast<const float4*>(&Xb[(size_t)s1 * NC + c4 * 4]);
        aB0.x += v0.x; aB0.y += v0.y; aB0.z += v0.z; aB0.w += v0.w;
        aB1.x += v1.x; aB1.y += v1.y; aB1.z += v1.z; aB1.w += v1.w;
      } else if (j < mB) {
        int rem = mB - j;
        if (rem >= 2) {
          int s0 = __shfl(eidB, j + h);
          float4 v0 = *reinterpret_cast<const float4*>(&Xb[(size_t)s0 * NC + c4 * 4]);
          aB0.x += v0.x; aB0.y += v0.y; aB0.z += v0.z; aB0.w += v0.w;
          if (rem == 3) {
            int s2 = __shfl(eidB, j + 2);
            if (h == 0) {
              float4 v2 = *reinterpret_cast<const float4*>(&Xb[(size_t)s2 * NC + c4 * 4]);
              aB0.x += v2.x; aB0.y += v2.y; aB0.z += v2.z; aB0.w += v2.w;
            }
          }
        } else {
          int s0 = __shfl(eidB, j);
          if (h == 0) {
            float4 v0 = *reinterpret_cast<const float4*>(&Xb[(size_t)s0 * NC + c4 * 4]);
            aB0.x += v0.x; aB0.y += v0.y; aB0.z += v0.z; aB0.w += v0.w;
          }
        }
      }
    }
    baseA += 64;
    baseB += 64;
  }

  // ---- final reduce + store, node A (original order) ----
  aA0.x += aA1.x; aA0.y += aA1.y; aA0.z += aA1.z; aA0.w += aA1.w;
  aA0.x += __shfl_xor(aA0.x, 32);
  aA0.y += __shfl_xor(aA0.y, 32);
  aA0.z += __shfl_xor(aA0.z, 32);
  aA0.w += __shfl_xor(aA0.w, 32);
  if (h == 0) {
    unsigned p0 = (unsigned)f2bf_rne(aA0.x) | ((unsigned)f2bf_rne(aA0.y) << 16);
    unsigned p1 = (unsigned)f2bf_rne(aA0.z) | ((unsigned)f2bf_rne(aA0.w) << 16);
    *reinterpret_cast<uint2*>(&H[((size_t)b * N0 + nodeA) * NC + c4 * 4]) = make_uint2(p0, p1);
  }
  // ---- node B ----
  if (hasB) {
    aB0.x += aB1.x; aB0.y += aB1.y; aB0.z += aB1.z; aB0.w += aB1.w;
    aB0.x += __shfl_xor(aB0.x, 32);
    aB0.y += __shfl_xor(aB0.y, 32);
    aB0.z += __shfl_xor(aB0.z, 32);
    aB0.w += __shfl_xor(aB0.w, 32);
    if (h == 0) {
      unsigned p0 = (unsigned)f2bf_rne(aB0.x) | ((unsigned)f2bf_rne(aB0.y) << 16);
      unsigned p1 = (unsigned)f2bf_rne(aB0.z) | ((unsigned)f2bf_rne(aB0.w) << 16);
      *reinterpret_cast<uint2*>(&H[((size_t)b * N0 + nodeB) * NC + c4 * 4]) = make_uint2(p0, p1);
    }
  }
}

// ---------- fused GIN MLP: x2 = relu(relu(h0@W1+b1)@W2+b2), fused score ----------
// Swapped mfma operands (D: lane=X-row, regs=4 W-cols -> float4 stores); W in LDS.
__global__ __launch_bounds__(256) void k_gin(const ushort_t* __restrict__ Xh,
                                             float* __restrict__ Xout,
                                             const ushort_t* __restrict__ W1t,
                                             const float* __restrict__ b1,
                                             const ushort_t* __restrict__ W2t,
                                             const float* __restrict__ b2,
                                             const float* __restrict__ pw,
                                             float* __restrict__ score, int n) {
  __shared__ ushort_t Ts[128 * 136];
  __shared__ ushort_t Wsh[128 * 136];
  int b = blockIdx.x & 7;
  int r0 = (blockIdx.x >> 3) * 128;
  int t = threadIdx.x;
  const ushort_t* Xg = Xh + (size_t)b * N0 * NC;

#pragma unroll
  for (int p = 0; p < 8; p++) {
    int id = t + p * 256;
    int row = id >> 4, seg = id & 15;
    short8 vh = (short8)0;
    if (r0 + row < n)
      vh = *reinterpret_cast<const short8*>(&Xg[(size_t)(r0 + row) * NC + seg * 8]);
    *reinterpret_cast<short8*>(&Ts[row * 136 + seg * 8]) = vh;
    *reinterpret_cast<short8*>(&Wsh[row * 136 + seg * 8]) =
        *reinterpret_cast<const short8*>(&W1t[row * NC + seg * 8]);
  }
  __syncthreads();

  int lane = t & 63, w = t >> 6;
  int li = lane & 15, lg = lane >> 4;
  int rbase = w * 32;

  f32x4 acc[2][8];
#pragma unroll
  for (int rt = 0; rt < 2; rt++)
#pragma unroll
    for (int ct = 0; ct < 8; ct++) acc[rt][ct] = (f32x4)0.f;

#pragma unroll
  for (int ks = 0; ks < 4; ks++) {
    short8 x0 = *reinterpret_cast<const short8*>(&Ts[(rbase + li) * 136 + ks * 32 + lg * 8]);
    short8 x1 = *reinterpret_cast<const short8*>(&Ts[(rbase + 16 + li) * 136 + ks * 32 + lg * 8]);
#pragma unroll
    for (int ct = 0; ct < 8; ct++) {
      short8 wf = *reinterpret_cast<const short8*>(&Wsh[(ct * 16 + li) * 136 + ks * 32 + lg * 8]);
      acc[0][ct] = __builtin_amdgcn_mfma_f32_16x16x32_bf16(wf, x0, acc[0][ct], 0, 0, 0);
      acc[1][ct] = __builtin_amdgcn_mfma_f32_16x16x32_bf16(wf, x1, acc[1][ct], 0, 0, 0);
    }
  }

#pragma unroll
  for (int rt = 0; rt < 2; rt++) {
    int row = rbase + rt * 16 + li;
#pragma unroll
    for (int ct = 0; ct < 8; ct++) {
      float4 bq = *reinterpret_cast<const float4*>(&b1[ct * 16 + lg * 4]);
      float o0 = fmaxf(acc[rt][ct][0] + bq.x, 0.f);
      float o1 = fmaxf(acc[rt][ct][1] + bq.y, 0.f);
      float o2 = fmaxf(acc[rt][ct][2] + bq.z, 0.f);
      float o3 = fmaxf(acc[rt][ct][3] + bq.w, 0.f);
      unsigned p0 = (unsigned)f2bf_rne(o0) | ((unsigned)f2bf_rne(o1) << 16);
      unsigned p1 = (unsigned)f2bf_rne(o2) | ((unsigned)f2bf_rne(o3) << 16);
      *reinterpret_cast<uint2*>(&Ts[row * 136 + ct * 16 + lg * 4]) = make_uint2(p0, p1);
    }
  }

  __syncthreads();
#pragma unroll
  for (int p = 0; p < 8; p++) {
    int id = t + p * 256;
    int row = id >> 4, seg = id & 15;
    *reinterpret_cast<short8*>(&Wsh[row * 136 + seg * 8]) =
        *reinterpret_cast<const short8*>(&W2t[row * NC + seg * 8]);
  }
  __syncthreads();

#pragma unroll
  for (int rt = 0; rt < 2; rt++)
#pragma unroll
    for (int ct = 0; ct < 8; ct++) acc[rt][ct] = (f32x4)0.f;

#pragma unroll
  for (int ks = 0; ks < 4; ks++) {
    short8 x0 = *reinterpret_cast<const short8*>(&Ts[(rbase + li) * 136 + ks * 32 + lg * 8]);
    short8 x1 = *reinterpret_cast<const short8*>(&Ts[(rbase + 16 + li) * 136 + ks * 32 + lg * 8]);
#pragma unroll
    for (int ct = 0; ct < 8; ct++) {
      short8 wf = *reinterpret_cast<const short8*>(&Wsh[(ct * 16 + li) * 136 + ks * 32 + lg * 8]);
      acc[0][ct] = __builtin_amdgcn_mfma_f32_16x16x32_bf16(wf, x0, acc[0][ct], 0, 0, 0);
      acc[1][ct] = __builtin_amdgcn_mfma_f32_16x16x32_bf16(wf, x1, acc[1][ct], 0, 0, 0);
    }
  }

  f32x4 pq[8];
  float psum = 0.f;
#pragma unroll
  for (int ct = 0; ct < 8; ct++) {
    pq[ct] = *reinterpret_cast<const f32x4*>(&pw[ct * 16 + lg * 4]);
    psum = fmaf(pq[ct][0], pq[ct][0], psum);
    psum = fmaf(pq[ct][1], pq[ct][1], psum);
    psum = fmaf(pq[ct][2], pq[ct][2], psum);
    psum = fmaf(pq[ct][3], pq[ct][3], psum);
  }
  psum += __shfl_xor(psum, 16);
  psum += __shfl_xor(psum, 32);
  float nrm = sqrtf(psum);

  float* Ob = Xout + (size_t)b * N0 * NC;
#pragma unroll
  for (int rt = 0; rt < 2; rt++) {
    int row = r0 + rbase + rt * 16 + li;
    bool ok = row < n;
    float dot = 0.f;
#pragma unroll
    for (int ct = 0; ct < 8; ct++) {
      float4 bq = *reinterpret_cast<const float4*>(&b2[ct * 16 + lg * 4]);
      float4 o;
      o.x = fmaxf(acc[rt][ct][0] + bq.x, 0.f);
      o.y = fmaxf(acc[rt][ct][1] + bq.y, 0.f);
      o.z = fmaxf(acc[rt][ct][2] + bq.z, 0.f);
      o.w = fmaxf(acc[rt][ct][3] + bq.w, 0.f);
      dot = fmaf(o.x, pq[ct][0], dot);
      dot = fmaf(o.y, pq[ct][1], dot);
      dot = fmaf(o.z, pq[ct][2], dot);
      dot = fmaf(o.w, pq[ct][3], dot);
      if (ok) *reinterpret_cast<float4*>(&Ob[(size_t)row * NC + ct * 16 + lg * 4]) = o;
    }
    dot += __shfl_xor(dot, 16);
    dot += __shfl_xor(dot, 32);
    if (lg == 0 && ok) score[b * N0 + row] = tanhf(dot / nrm);
  }
}

// ---------- top-k threshold via 4-pass radix select (parallel digit scan) ----------
__global__ __launch_bounds__(1024) void k_select(const float* __restrict__ score,
                                                 unsigned* __restrict__ vstar, int* __restrict__ quota,
                                                 int* __restrict__ gcnt, int* __restrict__ tcnt,
                                                 int n, int k) {
  __shared__ int hist[256];
  __shared__ int ss[257];
  __shared__ unsigned s_pref;
  __shared__ int s_r, s_gt;
  int b = blockIdx.x, t = threadIdx.x, lane = t & 63;
  if (t == 0) { s_pref = 0u; s_r = k; s_gt = 0; }
  __syncthreads();
  for (int pass = 0; pass < 4; ++pass) {
    int shift = 24 - pass * 8;
    if (t < 256) hist[t] = 0;
    __syncthreads();
    unsigned pref = s_pref;
    unsigned pmask = (pass == 0) ? 0u : (0xFFFFFFFFu << (shift + 8));
    for (int j0 = 0; j0 < n; j0 += 1024) {
      int j = j0 + t;
      unsigned key = (j < n) ? mono_u(score[b * N0 + j]) : 0u;
      unsigned d = (key >> shift) & 255;
      int contrib = (j < n) && ((key & pmask) == pref);
      unsigned long long bal = __ballot(contrib);
      if (bal == 0) continue;
      int fl = __ffsll((long long)bal) - 1;
      unsigned dref = __shfl(d, fl);
      if (__all(!contrib || d == dref)) {
        if (lane == fl) atomicAdd(&hist[dref], (int)__popcll(bal));
      } else if (contrib) {
        atomicAdd(&hist[d], 1);
      }
    }
    __syncthreads();
    if (t < 256) ss[t] = hist[t];
    __syncthreads();
    for (int o = 1; o < 256; o <<= 1) {
      int v = 0;
      if (t < 256) v = (t + o < 256) ? ss[t + o] : 0;
      __syncthreads();
      if (t < 256) ss[t] += v;
      __syncthreads();
    }
    int r = s_r;
    __syncthreads();
    if (t < 256) {
      int nxt = (t == 255) ? 0 : ss[t + 1];
      if (ss[t] >= r && nxt < r) {
        s_gt += nxt;
        s_r = r - nxt;
        s_pref = pref | ((unsigned)t << shift);
      }
    }
    __syncthreads();
  }
  if (t == 0) {
    vstar[b] = s_pref;
    quota[b] = k - s_gt;
  }
  __syncthreads();
  unsigned vs = s_pref;
  int w = t >> 6;
  int g = 0, tt = 0;
  for (int it = 0; it < 16; ++it) {
    int j = w * 1024 + it * 64 + lane;
    unsigned key = (j < n) ? mono_u(score[b * N0 + j]) : 0u;
    g += (int)__popcll(__ballot((j < n) && (key > vs)));
    tt += (int)__popcll(__ballot((j < n) && (key == vs)));
  }
  if (lane == 0) { gcnt[b * 16 + w] = g; tcnt[b * 16 + w] = tt; }
}

// ---------- map: assign new ids, jax.lax.top_k tie semantics ----------
__global__ __launch_bounds__(1024) void k_map_wr(const float* __restrict__ score,
                                                 const unsigned* __restrict__ vstar,
                                                 const int* __restrict__ quota,
                                                 const int* __restrict__ gcnt, const int* __restrict__ tcnt,
                                                 int* __restrict__ mp, int n) {
  __shared__ int wg[16], wt[16];
  __shared__ int s_gb, s_tb;
  int b = blockIdx.y, chunk = blockIdx.x, t = threadIdx.x;
  int lane = t & 63, wid = t >> 6;
  if (t == 0) {
    int gb = 0, tb = 0;
    for (int c = 0; c < chunk; c++) { gb += gcnt[b * 16 + c]; tb += tcnt[b * 16 + c]; }
    s_gb = gb; s_tb = tb;
  }
  int j = chunk * 1024 + t;
  unsigned vs = vstar[b];
  int q = quota[b];
  unsigned key = (j < n) ? mono_u(score[b * N0 + j]) : 0u;
  int gt = (j < n) && (key > vs);
  int tie = (j < n) && (key == vs);
  unsigned long long bg = __ballot(gt), bt = __ballot(tie);
  if (lane == 0) { wg[wid] = (int)__popcll(bg); wt[wid] = (int)__popcll(bt); }
  __syncthreads();
  if (j >= n) return;
  unsigned long long ltm = (lane == 63) ? ~0ull >> 1 : ((1ull << lane) - 1);
  int gloc = (int)__popcll(bg & ltm);
  int tloc = (int)__popcll(bt & ltm);
  for (int w = 0; w < 16; w++) {
    if (w < wid) { gloc += wg[w]; tloc += wt[w]; }
  }
  int tie_rank = s_tb + tloc;
  int sel = gt || (tie && tie_rank < q);
  int pos = s_gb + gloc + min(tie_rank, q);
  mp[b * N0 + j] = sel ? pos : -1;
}

// ---------- compact (fused readout, XCD-pinned): Xa[m] = x2[node]*val (f32) ----------
__global__ __launch_bounds__(256) void k_compact(const float* __restrict__ Xin,
                                                 float* __restrict__ Xout,
                                                 const int* __restrict__ mp,
                                                 const float* __restrict__ score,
                                                 int* __restrict__ maxbuf, float* __restrict__ sumbuf,
                                                 int n) {
  __shared__ float smx[128], ssm[128];
  int b = blockIdx.x & 7;
  int base = (blockIdx.x >> 3) * 64;
  if (base >= n) return;
  int c = threadIdx.x & 127, h = threadIdx.x >> 7;
  float mx = -INFINITY, sm = 0.f;
  for (int r = h; r < 64; r += 2) {
    int node = base + r;
    if (node >= n) break;
    int m = mp[b * N0 + node];
    if (m < 0) continue;
    float val = score[b * N0 + node];
    float v = Xin[((size_t)b * N0 + node) * NC + c] * val;
    Xout[((size_t)b * N0 + m) * NC + c] = v;
    mx = fmaxf(mx, v);
    sm += v;
  }
  if (h) { smx[c] = mx; ssm[c] = sm; }
  __syncthreads();
  if (!h) {
    mx = fmaxf(mx, smx[c]);
    sm += ssm[c];
    atomicMax(&maxbuf[b * NC + c], f2ikey(mx));
    atomicAdd(&sumbuf[b * NC + c], sm);
  }
}

// ---------- remap edges in place (XCD-pinned per graph); count next-depth degrees ----------
__global__ void k_remap(int* __restrict__ srcw, int* __restrict__ dstw,
                        const int* __restrict__ mp, int* __restrict__ cnt) {
  int b = blockIdx.x & 7;
  int bi = blockIdx.x >> 3;
  int nblk = gridDim.x >> 3;
  for (int e = bi * blockDim.x + threadIdx.x; e < NE; e += nblk * blockDim.x) {
    int i = b * NE + e;
    int d = dstw[i];
    if (d < 0) continue;
    int s = srcw[i];
    int ns = mp[b * N0 + s], nd = mp[b * N0 + d];
    if (ns >= 0 && nd >= 0) {
      srcw[i] = ns;
      dstw[i] = nd;
      atomicAdd(&cnt[b * N0 + nd], 1);
    } else {
      srcw[i] = 0;
      dstw[i] = -1;
    }
  }
}

// ---------- predictor MLP (folds readout-sum across depths) ----------
__global__ __launch_bounds__(256) void k_pred(const int* __restrict__ maxbuf,
                                              const float* __restrict__ sumbuf,
                                              const float* __restrict__ q1w, const float* __restrict__ q1b,
                                              const float* __restrict__ q2w, const float* __restrict__ q2b,
                                              const float* __restrict__ q3w, const float* __restrict__ q3b,
                                              float* __restrict__ out) {
  __shared__ float rr[256], h1[128], h2[64];
  int b = blockIdx.x, t = threadIdx.x;
  const float kdiv[4] = {13108.f, 10487.f, 8390.f, 6712.f};
  float acc = 0.f;
#pragma unroll
  for (int d = 0; d < 4; d++) {
    if (t < 128) acc += ikey2f(maxbuf[d * NB * NC + b * NC + t]);
    else acc += sumbuf[d * NB * NC + b * NC + (t - 128)] / kdiv[d];
  }
  rr[t] = acc;
  __syncthreads();
  if (t < 128) {
    float s = q1b[t];
    for (int j = 0; j < 256; j++) s = fmaf(rr[j], q1w[j * 128 + t], s);
    h1[t] = fmaxf(s, 0.f);
  }
  __syncthreads();
  if (t < 64) {
    float s = q2b[t];
    for (int j = 0; j < 128; j++) s = fmaf(h1[j], q2w[j * 64 + t], s);
    h2[t] = fmaxf(s, 0.f);
  }
  __syncthreads();
  if (t < 2) {
    float s = q3b[t];
    for (int j = 0; j < 64; j++) s = fmaf(h2[j], q3w[j * 2 + t], s);
    out[b * 2 + t] = s;
  }
}

// ---------- host orchestration ----------
extern "C" void kernel_launch(void* const* d_in, const int* in_sizes, int n_in,
                              void* d_out, int out_size, void* d_ws, size_t ws_size,
                              hipStream_t stream) {
  const float* x = (const float*)d_in[0];
  const int* src = (const int*)d_in[1];
  const int* dst = (const int*)d_in[2];
  const float* q1w = (const float*)d_in[23];
  const float* q1b = (const float*)d_in[24];
  const float* q2w = (const float*)d_in[25];
  const float* q2b = (const float*)d_in[26];
  const float* q3w = (const float*)d_in[27];
  const float* q3b = (const float*)d_in[28];

  char* p = (char*)d_ws;
  auto alloc = [&](size_t bytes) {
    char* q = p;
    p += (bytes + 255) & ~(size_t)255;
    return q;
  };
  float* Xa = (float*)alloc((size_t)NB * N0 * NC * 4);       // pooled x (f32)
  float* Xb = (float*)alloc((size_t)NB * N0 * NC * 4);       // x2 (f32, gin out)
  ushort_t* Xh = (ushort_t*)alloc((size_t)NB * N0 * NC * 2); // h0 (bf16)
  int* srcw = (int*)alloc((size_t)NB * NE * 4);
  int* dstw = (int*)alloc((size_t)NB * NE * 4);
  int* elist = (int*)alloc((size_t)NB * NE * 4);
  int* cnt = (int*)alloc((size_t)NB * N0 * 4);
  int* offs = (int*)alloc((size_t)NB * N0 * 4);
  int* cursor = (int*)alloc((size_t)NB * N0 * 4);
  float* score = (float*)alloc((size_t)NB * N0 * 4);
  int* mp = (int*)alloc((size_t)NB * N0 * 4);
  unsigned* vstar = (unsigned*)alloc(256);
  int* quota = (int*)alloc(256);
  int* gcnt = (int*)alloc(NB * 16 * 4);
  int* tcnt = (int*)alloc(NB * 16 * 4);
  int* maxbuf = (int*)alloc(4 * NB * NC * 4);
  float* sumbuf = (float*)alloc(4 * NB * NC * 4);
  ushort_t* Wt_all = (ushort_t*)alloc((size_t)8 * NC * NC * 2);

  hipMemsetAsync(cnt, 0, (size_t)NB * N0 * 4, stream);
  k_init<<<2048, 256, 0, stream>>>(src, dst, srcw, dstw, cnt, maxbuf, sumbuf);
  for (int i = 0; i < 4; i++) {
    k_wprep<<<64, 256, 0, stream>>>((const float*)d_in[3 + i * 5 + 0], Wt_all + (size_t)(2 * i) * NC * NC);
    k_wprep<<<64, 256, 0, stream>>>((const float*)d_in[3 + i * 5 + 2], Wt_all + (size_t)(2 * i + 1) * NC * NC);
  }

  static const int NSv[4] = {16384, 13108, 10487, 8390};
  static const int KSv[4] = {13108, 10487, 8390, 6712};
  for (int i = 0; i < 4; i++) {
    int n = NSv[i], k = KSv[i];
    const float* b1 = (const float*)d_in[3 + i * 5 + 1];
    const float* b2 = (const float*)d_in[3 + i * 5 + 3];
    const float* pw = (const float*)d_in[3 + i * 5 + 4];
    const ushort_t* w1t = Wt_all + (size_t)(2 * i) * NC * NC;
    const ushort_t* w2t = Wt_all + (size_t)(2 * i + 1) * NC * NC;
    const float* cur = (i == 0) ? x : Xa;

    k_scan<<<NB, 1024, 0, stream>>>(cnt, offs, cursor);
    k_fill<<<1024, 256, 0, stream>>>(srcw, dstw, cursor, elist);

    k_gather<<<((n + 7) / 8) * 8, 256, 0, stream>>>(cur, Xh, offs, cursor, elist, n);

    k_gin<<<((n + 127) / 128) * 8, 256, 0, stream>>>(Xh, Xb, w1t, b1, w2t, b2, pw, score, n);

    k_select<<<NB, 1024, 0, stream>>>(score, vstar, quota, gcnt, tcnt, n, k);
    dim3 gm(16, NB);
    k_map_wr<<<gm, 1024, 0, stream>>>(score, vstar, quota, gcnt, tcnt, mp, n);

    k_compact<<<((n + 63) / 64) * 8, 256, 0, stream>>>(Xb, Xa, mp, score,
                                                       maxbuf + i * NB * NC, sumbuf + i * NB * NC, n);
    k_remap<<<512, 256, 0, stream>>>(srcw, dstw, mp, cnt);
  }

  k_pred<<<NB, 256, 0, stream>>>(maxbuf, sumbuf, q1w, q1b, q2w, q2b, q3w, q3b, (float*)d_out);
}